// Round 1
// baseline (107.096 us; speedup 1.0000x reference)
//
#include <hip/hip_runtime.h>
#include <hip/hip_bf16.h>

// Alpha2Assoc: per-pixel D=32 chain, 3 layers of occlusion-weighted
// exclusive-cumprod transmittance. Memory-bound (537 MB traffic).

#define NUM_D 32
#define NUM_LAYERS 3
#define ALPHA_MIN 1e-4f

__global__ __launch_bounds__(256) void alpha2assoc_kernel(
    const float* __restrict__ in,   // [B, D, 1, H, W]
    float* __restrict__ out,        // [B, D, 3, H, W]
    int HW,                         // H*W
    int npix)                       // B*H*W
{
    int t = blockIdx.x * blockDim.x + threadIdx.x;
    if (t >= npix) return;

    int b = t / HW;
    int p = t - b * HW;

    const float* inb = in + (size_t)b * NUM_D * HW + p;
    float* outb = out + (size_t)b * NUM_D * NUM_LAYERS * HW + p;

    float a[NUM_D];
    float occ[NUM_D];

    // clip (lower bound only) — 32 independent coalesced dword loads
#pragma unroll
    for (int d = 0; d < NUM_D; ++d) {
        a[d] = fmaxf(inb[(size_t)d * HW], ALPHA_MIN);
        occ[d] = 1.0f;
    }

#pragma unroll
    for (int layer = 0; layer < NUM_LAYERS; ++layer) {
        float pr = 1.0f;  // running exclusive cumprod of (1 - a)
#pragma unroll
        for (int d = 0; d < NUM_D; ++d) {
            a[d] *= occ[d];                 // attenuate by prior occlusion
            float vis = pr;                  // exclusive cumprod value at plane d
            outb[((size_t)d * NUM_LAYERS + layer) * HW] = vis * occ[d];
            pr *= (1.0f - a[d]);
            occ[d] = 1.0f - vis;             // occlusion for next layer
        }
    }
}

extern "C" void kernel_launch(void* const* d_in, const int* in_sizes, int n_in,
                              void* d_out, int out_size, void* d_ws, size_t ws_size,
                              hipStream_t stream) {
    const float* in = (const float*)d_in[0];
    float* out = (float*)d_out;

    // alpha_imgs: [B, 32, 1, 512, 512]
    const int HW = 512 * 512;
    const int n = in_sizes[0];          // B*D*HW
    const int npix = n / NUM_D;         // B*HW

    int block = 256;
    int grid = (npix + block - 1) / block;
    alpha2assoc_kernel<<<grid, block, 0, stream>>>(in, out, HW, npix);
}